// Round 7
// baseline (73.446 us; speedup 1.0000x reference)
//
#include <hip/hip_runtime.h>

#define B_    1024
#define NIN_  128
#define NOUT_ 128
#define N_    512
#define EPS_  1e-5f
#define NPART 128         // stat-reduction partial blocks (8 rows each)

// k1: pure streaming masked channel-sum. No LDS, no barriers; waves independent.
// grid = B_, block = 512 (8 waves). Wave w owns channels [16w, 16w+16).
__global__ __launch_bounds__(512) void k1_masksum(
    const int* __restrict__ A, const float* __restrict__ x,
    const int* __restrict__ dil_p,
    float* __restrict__ sArr, float* __restrict__ outA)
{
    const int b = blockIdx.x;
    const int t = threadIdx.x;
    const int wave = t >> 6;
    const int lane = t & 63;
    const int dil = *dil_p;

    // Per-lane masks from direct coalesced int4 loads (lane's mask span ==
    // its x-load span). 8 waves re-read the same 2KB row: L1/L2-hit.
    const int* Arow = A + (size_t)b * N_;
    int4 a0 = *(const int4*)(Arow + lane * 4);
    int4 a1 = *(const int4*)(Arow + 256 + lane * 4);
    float mA[4], mB[4];
    mA[0] = (a0.x == dil || a0.x == -1) ? 1.f : 0.f;
    mA[1] = (a0.y == dil || a0.y == -1) ? 1.f : 0.f;
    mA[2] = (a0.z == dil || a0.z == -1) ? 1.f : 0.f;
    mA[3] = (a0.w == dil || a0.w == -1) ? 1.f : 0.f;
    mB[0] = (a1.x == dil || a1.x == -1) ? 1.f : 0.f;
    mB[1] = (a1.y == dil || a1.y == -1) ? 1.f : 0.f;
    mB[2] = (a1.z == dil || a1.z == -1) ? 1.f : 0.f;
    mB[3] = (a1.w == dil || a1.w == -1) ? 1.f : 0.f;

    if (wave == 0) {   // output 0: A passthrough as float (once per block)
        float4 f0 = {(float)a0.x, (float)a0.y, (float)a0.z, (float)a0.w};
        float4 f1 = {(float)a1.x, (float)a1.y, (float)a1.z, (float)a1.w};
        *(float4*)(outA + (size_t)b * N_ + lane * 4) = f0;
        *(float4*)(outA + (size_t)b * N_ + 256 + lane * 4) = f1;
    }

    const float* base = x + ((size_t)b * NIN_ + wave * 16) * N_;
    float* sRow = sArr + (size_t)b * NIN_ + wave * 16;

    // 2 channels per iteration (R5's best-measured form), plain cached loads
    for (int j = 0; j < 16; j += 2) {
        const float* row0 = base + (size_t)j * N_;
        const float* row1 = row0 + N_;
        float4 v0 = *(const float4*)(row0 + lane * 4);
        float4 v1 = *(const float4*)(row0 + 256 + lane * 4);
        float4 w0 = *(const float4*)(row1 + lane * 4);
        float4 w1 = *(const float4*)(row1 + 256 + lane * 4);
        float acc0 = v0.x * mA[0] + v0.y * mA[1] + v0.z * mA[2] + v0.w * mA[3]
                   + v1.x * mB[0] + v1.y * mB[1] + v1.z * mB[2] + v1.w * mB[3];
        float acc1 = w0.x * mA[0] + w0.y * mA[1] + w0.z * mA[2] + w0.w * mA[3]
                   + w1.x * mB[0] + w1.y * mB[1] + w1.z * mB[2] + w1.w * mB[3];
        #pragma unroll
        for (int off = 32; off > 0; off >>= 1) {
            acc0 += __shfl_xor(acc0, off, 64);
            acc1 += __shfl_xor(acc1, off, 64);
        }
        if (lane == 0) { sRow[j] = acc0; sRow[j + 1] = acc1; }
    }
}

// k2: linear (in registers) + 8-row partial batch-stats. Never writes h.
// grid = NPART, block = 256. Block j handles rows [8j, 8j+8).
__global__ __launch_bounds__(256) void k2_linear_stats(
    const float* __restrict__ sArr, const float* __restrict__ W,
    const float* __restrict__ bias,
    float* __restrict__ pS, float* __restrict__ pQ)
{
    const int j = blockIdx.x;
    const int t = threadIdx.x;
    __shared__ float ls[8][NIN_];
    ((float4*)ls)[t] = ((const float4*)(sArr + (size_t)j * 8 * NIN_))[t];
    __syncthreads();

    const int o = t & (NOUT_ - 1);
    const int half = t >> 7;                 // rows half, half+2, half+4, half+6
    const float* Wr = W + (size_t)o * NIN_;
    float b0 = bias[o];
    float acc0 = b0, acc1 = b0, acc2 = b0, acc3 = b0;
    #pragma unroll 8
    for (int i = 0; i < NIN_; ++i) {
        float w = Wr[i];
        acc0 += w * ls[half    ][i];         // ls[.][i] same addr across wave: broadcast
        acc1 += w * ls[half + 2][i];
        acc2 += w * ls[half + 4][i];
        acc3 += w * ls[half + 6][i];
    }
    float s4 = acc0 + acc1 + acc2 + acc3;
    float q4 = acc0 * acc0 + acc1 * acc1 + acc2 * acc2 + acc3 * acc3;
    __shared__ float rs[2][NOUT_], rq[2][NOUT_];
    rs[half][o] = s4; rq[half][o] = q4;
    __syncthreads();
    if (t < NOUT_) {
        pS[j * NOUT_ + t] = rs[0][t] + rs[1][t];
        pQ[j * NOUT_ + t] = rq[0][t] + rq[1][t];
    }
}

// k3: stats from 128 L2-hot partials + recompute h + normalize + ReLU.
// grid = B_/2, block = 256. Block handles 2 b-rows.
__global__ __launch_bounds__(256) void k3_norm(
    const float* __restrict__ sArr, const float* __restrict__ W,
    const float* __restrict__ bias, const float* __restrict__ pS,
    const float* __restrict__ pQ, const float* __restrict__ gamma,
    const float* __restrict__ beta, float* __restrict__ outF)
{
    const int t = threadIdx.x;
    const int o = t & (NOUT_ - 1);
    __shared__ float s2[2][NIN_];
    ((float*)s2)[t] = sArr[(size_t)blockIdx.x * 256 + t];
    __syncthreads();

    float S = 0.f, Q = 0.f;
    #pragma unroll 8
    for (int j = 0; j < NPART; ++j) {
        S += pS[(j << 7) + o];
        Q += pQ[(j << 7) + o];
    }
    float mean = S * (1.0f / B_);
    float var  = Q * (1.0f / B_) - mean * mean;   // biased, training mode
    float sc   = gamma[o] * rsqrtf(var + EPS_);
    float sh   = beta[o] - mean * sc;

    const int row = t >> 7;
    const float* Wr = W + (size_t)o * NIN_;
    float dot = bias[o];
    #pragma unroll 8
    for (int i = 0; i < NIN_; ++i) dot += Wr[i] * s2[row][i];

    float v = fmaf(dot, sc, sh);
    outF[(size_t)blockIdx.x * 256 + t] = fmaxf(v, 0.0f);
}

extern "C" void kernel_launch(void* const* d_in, const int* in_sizes, int n_in,
                              void* d_out, int out_size, void* d_ws, size_t ws_size,
                              hipStream_t stream) {
    const int*   A     = (const int*)d_in[0];
    const float* x     = (const float*)d_in[1];
    const float* W     = (const float*)d_in[2];
    const float* bias  = (const float*)d_in[3];
    const float* gamma = (const float*)d_in[4];
    const float* beta  = (const float*)d_in[5];
    const int*   dil   = (const int*)d_in[6];

    float* out  = (float*)d_out;
    float* outA = out;                       // B*1*N = 524288 floats (A passthrough)
    float* outF = out + (size_t)B_ * N_;     // B*NOUT = 131072 floats (features)

    float* sArr = (float*)d_ws;              // B*NIN floats = 512 KB
    float* pS   = sArr + (size_t)B_ * NIN_;  // NPART*NOUT floats = 64 KB
    float* pQ   = pS + NPART * NOUT_;        // NPART*NOUT floats = 64 KB

    k1_masksum<<<B_, 512, 0, stream>>>(A, x, dil, sArr, outA);
    k2_linear_stats<<<NPART, 256, 0, stream>>>(sArr, W, bias, pS, pQ);
    k3_norm<<<B_ / 2, 256, 0, stream>>>(sArr, W, bias, pS, pQ, gamma, beta, outF);
}

// Round 8
// 68.347 us; speedup vs baseline: 1.0746x; 1.0746x over previous
//
#include <hip/hip_runtime.h>

#define B_    1024
#define NIN_  128
#define NOUT_ 128
#define N_    512
#define EPS_  1e-5f
#define NPART 128         // stat-reduction partial blocks (8 rows each)

// k1: streaming masked channel-sum. R5's interleaved footprint (8 waves cover
// 16 ADJACENT channels at any instant — contiguous 32KB front per block),
// but barrier-free: direct-load masks, direct global s-writes, no epilogue.
// grid = B_, block = 512.
__global__ __launch_bounds__(512) void k1_masksum(
    const int* __restrict__ A, const float* __restrict__ x,
    const int* __restrict__ dil_p,
    float* __restrict__ sArr, float* __restrict__ outA)
{
    const int b = blockIdx.x;
    const int t = threadIdx.x;
    const int wave = t >> 6;
    const int lane = t & 63;
    const int dil = *dil_p;

    // Per-lane masks from direct coalesced int4 loads (lane's mask span ==
    // its x-load span). 8 waves re-read the same 2KB row: L1-hit.
    const int* Arow = A + (size_t)b * N_;
    int4 a0 = *(const int4*)(Arow + lane * 4);
    int4 a1 = *(const int4*)(Arow + 256 + lane * 4);
    float mA[4], mB[4];
    mA[0] = (a0.x == dil || a0.x == -1) ? 1.f : 0.f;
    mA[1] = (a0.y == dil || a0.y == -1) ? 1.f : 0.f;
    mA[2] = (a0.z == dil || a0.z == -1) ? 1.f : 0.f;
    mA[3] = (a0.w == dil || a0.w == -1) ? 1.f : 0.f;
    mB[0] = (a1.x == dil || a1.x == -1) ? 1.f : 0.f;
    mB[1] = (a1.y == dil || a1.y == -1) ? 1.f : 0.f;
    mB[2] = (a1.z == dil || a1.z == -1) ? 1.f : 0.f;
    mB[3] = (a1.w == dil || a1.w == -1) ? 1.f : 0.f;

    if (wave == 0) {   // output 0: A passthrough as float (once per block)
        float4 f0 = {(float)a0.x, (float)a0.y, (float)a0.z, (float)a0.w};
        float4 f1 = {(float)a1.x, (float)a1.y, (float)a1.z, (float)a1.w};
        *(float4*)(outA + (size_t)b * N_ + lane * 4) = f0;
        *(float4*)(outA + (size_t)b * N_ + 256 + lane * 4) = f1;
    }

    const float* base = x + (size_t)b * NIN_ * N_;
    float* sRow = sArr + (size_t)b * NIN_;

    // R5's exact loop shape: 2 adjacent channels per iter, interleaved across
    // waves (i = 2*wave + 16*k). Plain cached loads (nt = -35% BW, R3).
    for (int i = wave * 2; i < NIN_; i += 16) {
        const float* row0 = base + (size_t)i * N_;
        const float* row1 = row0 + N_;
        float4 v0 = *(const float4*)(row0 + lane * 4);
        float4 v1 = *(const float4*)(row0 + 256 + lane * 4);
        float4 w0 = *(const float4*)(row1 + lane * 4);
        float4 w1 = *(const float4*)(row1 + 256 + lane * 4);
        float acc0 = v0.x * mA[0] + v0.y * mA[1] + v0.z * mA[2] + v0.w * mA[3]
                   + v1.x * mB[0] + v1.y * mB[1] + v1.z * mB[2] + v1.w * mB[3];
        float acc1 = w0.x * mA[0] + w0.y * mA[1] + w0.z * mA[2] + w0.w * mA[3]
                   + w1.x * mB[0] + w1.y * mB[1] + w1.z * mB[2] + w1.w * mB[3];
        #pragma unroll
        for (int off = 32; off > 0; off >>= 1) {
            acc0 += __shfl_xor(acc0, off, 64);
            acc1 += __shfl_xor(acc1, off, 64);
        }
        if (lane == 0) { sRow[i] = acc0; sRow[i + 1] = acc1; }
    }
}

// k2: linear (in registers) + 8-row partial batch-stats. Never writes h.
// grid = NPART, block = 256. Block j handles rows [8j, 8j+8).
__global__ __launch_bounds__(256) void k2_linear_stats(
    const float* __restrict__ sArr, const float* __restrict__ W,
    const float* __restrict__ bias,
    float* __restrict__ pS, float* __restrict__ pQ)
{
    const int j = blockIdx.x;
    const int t = threadIdx.x;
    __shared__ float ls[8][NIN_];
    ((float4*)ls)[t] = ((const float4*)(sArr + (size_t)j * 8 * NIN_))[t];
    __syncthreads();

    const int o = t & (NOUT_ - 1);
    const int half = t >> 7;                 // rows half, half+2, half+4, half+6
    const float* Wr = W + (size_t)o * NIN_;
    float b0 = bias[o];
    float acc0 = b0, acc1 = b0, acc2 = b0, acc3 = b0;
    #pragma unroll 8
    for (int i = 0; i < NIN_; ++i) {
        float w = Wr[i];
        acc0 += w * ls[half    ][i];         // ls[.][i] same addr across wave: broadcast
        acc1 += w * ls[half + 2][i];
        acc2 += w * ls[half + 4][i];
        acc3 += w * ls[half + 6][i];
    }
    float s4 = acc0 + acc1 + acc2 + acc3;
    float q4 = acc0 * acc0 + acc1 * acc1 + acc2 * acc2 + acc3 * acc3;
    __shared__ float rs[2][NOUT_], rq[2][NOUT_];
    rs[half][o] = s4; rq[half][o] = q4;
    __syncthreads();
    if (t < NOUT_) {
        pS[j * NOUT_ + t] = rs[0][t] + rs[1][t];
        pQ[j * NOUT_ + t] = rq[0][t] + rq[1][t];
    }
}

// k3: stats from 128 L2-hot partials + recompute h + normalize + ReLU.
// grid = B_/2, block = 256. Block handles 2 b-rows.
__global__ __launch_bounds__(256) void k3_norm(
    const float* __restrict__ sArr, const float* __restrict__ W,
    const float* __restrict__ bias, const float* __restrict__ pS,
    const float* __restrict__ pQ, const float* __restrict__ gamma,
    const float* __restrict__ beta, float* __restrict__ outF)
{
    const int t = threadIdx.x;
    const int o = t & (NOUT_ - 1);
    __shared__ float s2[2][NIN_];
    ((float*)s2)[t] = sArr[(size_t)blockIdx.x * 256 + t];
    __syncthreads();

    float S = 0.f, Q = 0.f;
    #pragma unroll 8
    for (int j = 0; j < NPART; ++j) {
        S += pS[(j << 7) + o];
        Q += pQ[(j << 7) + o];
    }
    float mean = S * (1.0f / B_);
    float var  = Q * (1.0f / B_) - mean * mean;   // biased, training mode
    float sc   = gamma[o] * rsqrtf(var + EPS_);
    float sh   = beta[o] - mean * sc;

    const int row = t >> 7;
    const float* Wr = W + (size_t)o * NIN_;
    float dot = bias[o];
    #pragma unroll 8
    for (int i = 0; i < NIN_; ++i) dot += Wr[i] * s2[row][i];

    float v = fmaf(dot, sc, sh);
    outF[(size_t)blockIdx.x * 256 + t] = fmaxf(v, 0.0f);
}

extern "C" void kernel_launch(void* const* d_in, const int* in_sizes, int n_in,
                              void* d_out, int out_size, void* d_ws, size_t ws_size,
                              hipStream_t stream) {
    const int*   A     = (const int*)d_in[0];
    const float* x     = (const float*)d_in[1];
    const float* W     = (const float*)d_in[2];
    const float* bias  = (const float*)d_in[3];
    const float* gamma = (const float*)d_in[4];
    const float* beta  = (const float*)d_in[5];
    const int*   dil   = (const int*)d_in[6];

    float* out  = (float*)d_out;
    float* outA = out;                       // B*1*N = 524288 floats (A passthrough)
    float* outF = out + (size_t)B_ * N_;     // B*NOUT = 131072 floats (features)

    float* sArr = (float*)d_ws;              // B*NIN floats = 512 KB
    float* pS   = sArr + (size_t)B_ * NIN_;  // NPART*NOUT floats = 64 KB
    float* pQ   = pS + NPART * NOUT_;        // NPART*NOUT floats = 64 KB

    k1_masksum<<<B_, 512, 0, stream>>>(A, x, dil, sArr, outA);
    k2_linear_stats<<<NPART, 256, 0, stream>>>(sArr, W, bias, pS, pQ);
    k3_norm<<<B_ / 2, 256, 0, stream>>>(sArr, W, bias, pS, pQ, gamma, beta, outF);
}

// Round 9
// 54.912 us; speedup vs baseline: 1.3375x; 1.2447x over previous
//
#include <hip/hip_runtime.h>

#define B_    1024
#define NIN_  128
#define NOUT_ 128
#define N_    512
#define EPS_  1e-5f
#define NPART 16          // stat-reduction partial blocks

// k1: masked reduce over n + fused 128x128 linear
// grid = B_, block = 512 (8 waves). Measured-best structure (R5, 54.8us):
// LDS mask staging, interleaved channel pairs (2/iter), LDS s + W-dot epilogue.
// Variants measured worse: 8-wide ILP batch (R6 +2.7us), chunked channels
// (R7 +18.7us), barrier-free direct-store (R8 +13.5us), nt loads (R3 +19us),
// global atomics for stats (R4 +16us).
__global__ __launch_bounds__(512) void k1_maskreduce_linear(
    const int* __restrict__ A, const float* __restrict__ x,
    const float* __restrict__ W, const float* __restrict__ bias,
    const int* __restrict__ dil_p, float* __restrict__ h,
    float* __restrict__ outA)
{
    __shared__ float m[N_];
    __shared__ float s[NIN_];
    const int b = blockIdx.x;
    const int t = threadIdx.x;
    const int dil = *dil_p;

    // Load A row, build mask in LDS, and emit output 0 (A as float)
    const int* Arow = A + (size_t)b * N_;
    float* oA = outA + (size_t)b * N_;
    {
        int n = t;               // 512 threads, N_=512: one element each
        int a = Arow[n];
        m[n] = (a == dil || a == -1) ? 1.0f : 0.0f;
        oA[n] = (float)a;
    }
    __syncthreads();

    const int wave = t >> 6;
    const int lane = t & 63;

    // Per-lane mask registers: lane l covers n in [4l,4l+4) and [256+4l,256+4l+4)
    float mA[4], mB[4];
    #pragma unroll
    for (int j = 0; j < 4; ++j) {
        mA[j] = m[lane * 4 + j];
        mB[j] = m[256 + lane * 4 + j];
    }

    // 8 waves, 2 adjacent channels per iteration (two independent shuffle
    // chains overlap; 8 iterations). Plain cached loads.
    for (int i = wave * 2; i < NIN_; i += 16) {
        const float* row0 = x + ((size_t)b * NIN_ + i) * N_;
        const float* row1 = row0 + N_;
        float4 a0 = *(const float4*)(row0 + lane * 4);
        float4 a1 = *(const float4*)(row0 + 256 + lane * 4);
        float4 b0 = *(const float4*)(row1 + lane * 4);
        float4 b1 = *(const float4*)(row1 + 256 + lane * 4);
        float acc0 = a0.x * mA[0] + a0.y * mA[1] + a0.z * mA[2] + a0.w * mA[3]
                   + a1.x * mB[0] + a1.y * mB[1] + a1.z * mB[2] + a1.w * mB[3];
        float acc1 = b0.x * mA[0] + b0.y * mA[1] + b0.z * mA[2] + b0.w * mA[3]
                   + b1.x * mB[0] + b1.y * mB[1] + b1.z * mB[2] + b1.w * mB[3];
        #pragma unroll
        for (int off = 32; off > 0; off >>= 1) {
            acc0 += __shfl_xor(acc0, off, 64);
            acc1 += __shfl_xor(acc1, off, 64);
        }
        if (lane == 0) { s[i] = acc0; s[i + 1] = acc1; }
    }
    __syncthreads();

    // h[b,o] = bias[o] + sum_i W[o,i] * s[i]   (threads 0..127; W L2-resident)
    if (t < NOUT_) {
        const float* Wr = W + (size_t)t * NIN_;
        float acc = bias[t];
        #pragma unroll 8
        for (int i = 0; i < NIN_; ++i) acc += Wr[i] * s[i];
        h[(size_t)b * NOUT_ + t] = acc;
    }
}

// k2: coalesced two-level batch-stat partials.
// grid = NPART, block = 256. Block j reduces h[64j .. 64j+64, :].
__global__ __launch_bounds__(256) void k2_partial(
    const float* __restrict__ h, float* __restrict__ pS, float* __restrict__ pQ)
{
    const int j = blockIdx.x;
    const int t = threadIdx.x;
    const int o = t & (NOUT_ - 1);
    const int half = t >> 7;             // 0 or 1: rows [0,32) or [32,64)
    const float* base = h + ((size_t)j * 64 + half * 32) * NOUT_;
    float s = 0.f, q = 0.f;
    #pragma unroll 8
    for (int r = 0; r < 32; ++r) {
        float v = base[(size_t)r * NOUT_ + o];   // consecutive t -> consecutive addr
        s += v; q += v * v;
    }
    __shared__ float ls[2][NOUT_], lq[2][NOUT_];
    ls[half][o] = s; lq[half][o] = q;
    __syncthreads();
    if (t < NOUT_) {
        pS[j * NOUT_ + t] = ls[0][t] + ls[1][t];
        pQ[j * NOUT_ + t] = lq[0][t] + lq[1][t];
    }
}

// k3: stats from partials (L2-hot) + normalize + ReLU
// grid = B_*NOUT_/256, block = 256
__global__ __launch_bounds__(256) void k3_norm(
    const float* __restrict__ h, const float* __restrict__ pS,
    const float* __restrict__ pQ, const float* __restrict__ gamma,
    const float* __restrict__ beta, float* __restrict__ outF)
{
    const int idx = blockIdx.x * 256 + threadIdx.x;
    const int o = idx & (NOUT_ - 1);
    float S = 0.f, Q = 0.f;
    #pragma unroll
    for (int j = 0; j < NPART; ++j) {
        S += pS[j * NOUT_ + o];
        Q += pQ[j * NOUT_ + o];
    }
    float mean = S * (1.0f / B_);
    float var  = Q * (1.0f / B_) - mean * mean;   // biased, training mode
    float sc   = gamma[o] * rsqrtf(var + EPS_);
    float sh   = beta[o] - mean * sc;
    float v = fmaf(h[idx], sc, sh);
    outF[idx] = fmaxf(v, 0.0f);
}

extern "C" void kernel_launch(void* const* d_in, const int* in_sizes, int n_in,
                              void* d_out, int out_size, void* d_ws, size_t ws_size,
                              hipStream_t stream) {
    const int*   A     = (const int*)d_in[0];
    const float* x     = (const float*)d_in[1];
    const float* W     = (const float*)d_in[2];
    const float* bias  = (const float*)d_in[3];
    const float* gamma = (const float*)d_in[4];
    const float* beta  = (const float*)d_in[5];
    const int*   dil   = (const int*)d_in[6];

    float* out  = (float*)d_out;
    float* outA = out;                       // B*1*N = 524288 floats (A passthrough)
    float* outF = out + (size_t)B_ * N_;     // B*NOUT = 131072 floats (features)

    float* h  = (float*)d_ws;                // B*NOUT floats = 512 KB
    float* pS = h + (size_t)B_ * NOUT_;      // NPART*NOUT floats
    float* pQ = pS + NPART * NOUT_;          // NPART*NOUT floats

    k1_maskreduce_linear<<<B_, 512, 0, stream>>>(A, x, W, bias, dil, h, outA);
    k2_partial<<<NPART, 256, 0, stream>>>(h, pS, pQ);
    k3_norm<<<(B_ * NOUT_) / 256, 256, 0, stream>>>(h, pS, pQ, gamma, beta, outF);
}